// Round 7
// baseline (653.789 us; speedup 1.0000x reference)
//
#include <hip/hip_runtime.h>
#include <math.h>

typedef __attribute__((ext_vector_type(8))) __bf16 bf16x8;
typedef __attribute__((ext_vector_type(4))) float f32x4;

__device__ inline unsigned short f2bf(float f) {  // RNE
    unsigned int i = __float_as_uint(f);
    unsigned int r = i + 0x7fffu + ((i >> 16) & 1u);
    return (unsigned short)(r >> 16);
}
__device__ inline float bf2f(unsigned short u) {
    return __uint_as_float(((unsigned int)u) << 16);
}

#define F2BF_B 329  // ceil(83968/256)
#define U_B 3       // ceil(640/256)

// ---------------- prelude: MLP(8 thr/node) + weight-cast + graph starts + u=W^T a + hist --
__global__ __launch_bounds__(256) void prelude_kernel(
    const float* __restrict__ x,
    const float* __restrict__ w1, const float* __restrict__ b1,
    const float* __restrict__ w2, const float* __restrict__ b2,
    const float* __restrict__ w3, const float* __restrict__ b3,
    unsigned short* __restrict__ h0, int n,
    const float* __restrict__ g0, const float* __restrict__ g1, const float* __restrict__ g2,
    const float* __restrict__ g3, const float* __restrict__ g4,
    unsigned short* __restrict__ wbAll,
    const float* __restrict__ s0, const float* __restrict__ s1, const float* __restrict__ s2,
    const float* __restrict__ s3, const float* __restrict__ s4,
    const float* __restrict__ d0, const float* __restrict__ d1, const float* __restrict__ d2,
    const float* __restrict__ d3, const float* __restrict__ d4,
    float* __restrict__ uAll,
    const int* __restrict__ batch, int* __restrict__ gstart, int G,
    const int* __restrict__ dst, int* __restrict__ deg, int E,
    int mlpB, int gsB) {
    int b = blockIdx.x;
    int tid = threadIdx.x;
    if (b < mlpB) {
        // 32 nodes/block, 8 threads/node (oct), sw3 transposed: <=2-way LDS aliasing
        __shared__ float sw1[16], sb1[16], sw2[512], sb2[32], sw3t[2048], sb3[64];
        if (tid < 16) { sw1[tid] = w1[tid]; sb1[tid] = b1[tid]; }
        if (tid < 32) sb2[tid] = b2[tid];
        if (tid < 64) sb3[tid] = b3[tid];
        for (int i = tid; i < 512; i += 256) sw2[i] = w2[i];
        for (int i = tid; i < 2048; i += 256) {
            int ii = i >> 6, o = i & 63;
            sw3t[i] = w3[o * 32 + ii];
        }
        __syncthreads();
        int node = b * 32 + (tid >> 3), oct = tid & 7;
        if (node >= n) return;
        float xv = x[node];
        float t1[16], t2[32];
#pragma unroll
        for (int i = 0; i < 16; i++) t1[i] = fmaxf(sw1[i] * xv + sb1[i], 0.f);
#pragma unroll
        for (int o = 0; o < 32; o++) {
            float a = sb2[o];
#pragma unroll
            for (int i = 0; i < 16; i++) a += sw2[o * 16 + i] * t1[i];
            t2[o] = fmaxf(a, 0.f);
        }
        float av[8];
#pragma unroll
        for (int j = 0; j < 8; j++) av[j] = sb3[oct * 8 + j];
#pragma unroll
        for (int i = 0; i < 32; i++) {
            float t = t2[i];
#pragma unroll
            for (int j = 0; j < 8; j++) av[j] += sw3t[i * 64 + oct * 8 + j] * t;
        }
        unsigned int wv[4];
#pragma unroll
        for (int p = 0; p < 4; p++)
            wv[p] = (unsigned)f2bf(fmaxf(av[2 * p], 0.f)) |
                    ((unsigned)f2bf(fmaxf(av[2 * p + 1], 0.f)) << 16);
        ((uint4*)(h0 + (size_t)node * 64 + oct * 8))[0] = make_uint4(wv[0], wv[1], wv[2], wv[3]);
    } else if (b < mlpB + F2BF_B) {
        int i = (b - mlpB) * 256 + tid;
        // weight segment offsets: 0, 8192, 40960, 73728, 81920, end 83968
        float v;
        if (i < 8192) v = g0[i];
        else if (i < 40960) v = g1[i - 8192];
        else if (i < 73728) v = g2[i - 40960];
        else if (i < 81920) v = g3[i - 73728];
        else if (i < 83968) v = g4[i - 81920];
        else return;
        wbAll[i] = f2bf(v);
    } else if (b < mlpB + F2BF_B + gsB) {
        int g = (b - mlpB - F2BF_B) * 256 + tid;
        if (g > G) return;
        if (g == G) { gstart[G] = n; return; }
        int lo = 0, hi = n;
        while (lo < hi) {
            int mid = (lo + hi) >> 1;
            if (batch[mid] < g) lo = mid + 1;
            else hi = mid;
        }
        gstart[g] = lo;
    } else if (b < mlpB + F2BF_B + gsB + U_B) {
        // u_s[k] = sum_o W[o][k]*a_s[o]; layers packed at {0,64,192,448,576}, total 640
        int idx = (b - mlpB - F2BF_B - gsB) * 256 + tid;
        if (idx >= 640) return;
        int l, st, K, O;
        if (idx < 64) { l = 0; st = 0; K = 64; O = 128; }
        else if (idx < 192) { l = 1; st = 64; K = 128; O = 256; }
        else if (idx < 448) { l = 2; st = 192; K = 256; O = 128; }
        else if (idx < 576) { l = 3; st = 448; K = 128; O = 64; }
        else { l = 4; st = 576; K = 64; O = 32; }
        const float* W = (l == 0) ? g0 : (l == 1) ? g1 : (l == 2) ? g2 : (l == 3) ? g3 : g4;
        const float* as = (l == 0) ? s0 : (l == 1) ? s1 : (l == 2) ? s2 : (l == 3) ? s3 : s4;
        const float* ad = (l == 0) ? d0 : (l == 1) ? d1 : (l == 2) ? d2 : (l == 3) ? d3 : d4;
        int k = idx - st;
        float us = 0.f, ud = 0.f;
        for (int o = 0; o < O; o++) {
            float w = W[o * K + k];
            us += w * as[o];
            ud += w * ad[o];
        }
        uAll[idx] = us;
        uAll[640 + idx] = ud;
    } else {
        int e = (b - mlpB - F2BF_B - gsB - U_B) * 256 + tid;
        if (e >= E + n) return;
        int d = (e < E) ? dst[e] : (e - E);
        atomicAdd(&deg[d], 1);
    }
}

// ---------------- bf16 MFMA GEMM, 128xBN tile, BK=64; y==0 blocks also emit as_/ad_ -------
// as_[r] = A[r,:] . us (fp32), ad_ likewise — no atomics, no zeroing needed.
template <int BN>
__global__ __launch_bounds__(256) void gemm_mfma(
    const unsigned short* __restrict__ A, const unsigned short* __restrict__ Wb,
    unsigned short* __restrict__ Cb,
    const float* __restrict__ us, const float* __restrict__ ud,
    float* __restrict__ as_, float* __restrict__ ad_, int n, int K, int O) {
    constexpr int SN = BN / 32;
    __shared__ unsigned short As[128][72];  // +8 pad: frag reads <=2-way banks (free)
    __shared__ unsigned short Ws[BN][72];
    int tid = threadIdx.x;
    int row0 = blockIdx.x * 128, col0 = blockIdx.y * BN;
    int w = tid >> 6, lane = tid & 63;
    int wr = w >> 1, wc = w & 1;
    int quad = lane >> 4, l15 = lane & 15;
    f32x4 acc[4][SN];
#pragma unroll
    for (int mi = 0; mi < 4; mi++)
#pragma unroll
        for (int ni = 0; ni < SN; ni++) acc[mi][ni] = (f32x4){0.f, 0.f, 0.f, 0.f};
    float uacc_s = 0.f, uacc_d = 0.f;
    int urow = tid & 127, uhalf = tid >> 7;

    for (int k0 = 0; k0 < K; k0 += 64) {
#pragma unroll
        for (int i = tid; i < 1024; i += 256) {
            int r = i >> 3, c8 = i & 7;
            int gr = row0 + r;
            uint4 v = make_uint4(0u, 0u, 0u, 0u);
            if (gr < n) v = *(const uint4*)(A + (size_t)gr * K + k0 + c8 * 8);
            *(uint4*)&As[r][c8 * 8] = v;
        }
#pragma unroll
        for (int i = tid; i < BN * 8; i += 256) {
            int r = i >> 3, c8 = i & 7;
            uint4 v = *(const uint4*)(Wb + (size_t)(col0 + r) * K + k0 + c8 * 8);
            *(uint4*)&Ws[r][c8 * 8] = v;
        }
        __syncthreads();
        if (col0 == 0) {
            // alpha-logit partial dots from the staged A tile (uint2 = 4 bf16 per read)
            int kb = uhalf * 32;
#pragma unroll
            for (int q = 0; q < 8; q++) {
                uint2 rawv = *(const uint2*)&As[urow][kb + q * 4];
                float a0 = __uint_as_float(rawv.x << 16);
                float a1 = __uint_as_float(rawv.x & 0xffff0000u);
                float a2 = __uint_as_float(rawv.y << 16);
                float a3 = __uint_as_float(rawv.y & 0xffff0000u);
                int kk = k0 + kb + q * 4;
                uacc_s += a0 * us[kk] + a1 * us[kk + 1] + a2 * us[kk + 2] + a3 * us[kk + 3];
                uacc_d += a0 * ud[kk] + a1 * ud[kk + 1] + a2 * ud[kk + 2] + a3 * ud[kk + 3];
            }
        }
#pragma unroll
        for (int kk = 0; kk < 64; kk += 32) {
            bf16x8 bfr[SN];
#pragma unroll
            for (int ni = 0; ni < SN; ni++)
                bfr[ni] = *(const bf16x8*)&Ws[wc * (BN / 2) + ni * 16 + l15][kk + quad * 8];
#pragma unroll
            for (int mi = 0; mi < 4; mi++) {
                bf16x8 afr = *(const bf16x8*)&As[wr * 64 + mi * 16 + l15][kk + quad * 8];
#pragma unroll
                for (int ni = 0; ni < SN; ni++)
                    acc[mi][ni] = __builtin_amdgcn_mfma_f32_16x16x32_bf16(afr, bfr[ni],
                                                                          acc[mi][ni], 0, 0, 0);
            }
        }
        __syncthreads();
    }
    if (col0 == 0) {
        float* red = (float*)&As[0][0];
        red[tid] = uacc_s;
        red[256 + tid] = uacc_d;
        __syncthreads();
        if (tid < 128) {
            int gr = row0 + tid;
            if (gr < n) {
                as_[gr] = red[tid] + red[tid + 128];
                ad_[gr] = red[256 + tid] + red[384 + tid];
            }
        }
    }
    int gc[SN];
#pragma unroll
    for (int ni = 0; ni < SN; ni++) gc[ni] = col0 + wc * (BN / 2) + ni * 16 + l15;
#pragma unroll
    for (int mi = 0; mi < 4; mi++) {
        int gm0 = row0 + wr * 64 + mi * 16 + quad * 4;
#pragma unroll
        for (int ni = 0; ni < SN; ni++) {
#pragma unroll
            for (int r = 0; r < 4; r++) {
                int gm = gm0 + r;
                if (gm < n) Cb[(size_t)gm * O + gc[ni]] = f2bf(acc[mi][ni][r]);
            }
        }
    }
}

// ---------------- scan: per-1024-chunk sums ----------------
__global__ void scan_block_sums(const int* __restrict__ deg, int* __restrict__ bsums, int n) {
    __shared__ int sdata[256];
    int tid = threadIdx.x;
    int base = blockIdx.x * 1024 + tid * 4;
    int s = 0;
    for (int i = 0; i < 4; i++) {
        int g = base + i;
        if (g < n) s += deg[g];
    }
    sdata[tid] = s;
    __syncthreads();
    for (int off = 128; off > 0; off >>= 1) {
        if (tid < off) sdata[tid] += sdata[tid + off];
        __syncthreads();
    }
    if (tid == 0) bsums[blockIdx.x] = sdata[0];
}

// ---------------- scan_write: inline bsums prefix (nb <= 256) + rowptr/cursor -------------
__global__ void scan_write(const int* __restrict__ deg, const int* __restrict__ bsums,
                           int* __restrict__ rowptr, int* __restrict__ cursor, int n, int nb) {
    __shared__ int sdata[256];
    int tid = threadIdx.x;
    sdata[tid] = (tid < blockIdx.x && tid < nb) ? bsums[tid] : 0;
    __syncthreads();
    for (int off = 128; off > 0; off >>= 1) {
        if (tid < off) sdata[tid] += sdata[tid + off];
        __syncthreads();
    }
    int base = sdata[0];
    __syncthreads();
    int gbase = blockIdx.x * 1024 + tid * 4;
    int v[4];
    int s = 0;
    for (int i = 0; i < 4; i++) {
        int g = gbase + i;
        v[i] = (g < n) ? deg[g] : 0;
        s += v[i];
    }
    sdata[tid] = s;
    __syncthreads();
    for (int off = 1; off < 256; off <<= 1) {
        int t = (tid >= off) ? sdata[tid - off] : 0;
        __syncthreads();
        sdata[tid] += t;
        __syncthreads();
    }
    int excl = sdata[tid] - s + base;
    for (int i = 0; i < 4; i++) {
        int g = gbase + i;
        if (g < n) { rowptr[g] = excl; cursor[g] = excl; }
        excl += v[i];
    }
    if (blockIdx.x == gridDim.x - 1 && tid == 255) rowptr[n] = base + sdata[255];
}

__global__ void scatter_kernel(const int* __restrict__ esrc_in, const int* __restrict__ edst_in,
                               int* __restrict__ cursor, int* __restrict__ esrc, int E, int n) {
    int e = blockIdx.x * 256 + threadIdx.x;
    if (e >= E + n) return;
    int s, d;
    if (e < E) { s = esrc_in[e]; d = edst_in[e]; }
    else { s = e - E; d = e - E; }
    int pos = atomicAdd(&cursor[d], 1);
    esrc[pos] = s;
}

// ---------------- GAT aggregation: one wave per dst node, bf16 features ----------------
template <int O>
__global__ __launch_bounds__(256) void gat_aggregate(
    const unsigned short* __restrict__ hl, const float* __restrict__ as_,
    const float* __restrict__ ad_, const int* __restrict__ rowptr,
    const int* __restrict__ esrc, const float* __restrict__ bias,
    unsigned short* __restrict__ hout, int n) {
    constexpr int C8 = O / 8;
    constexpr int EPW = 64 / C8;
    int v = blockIdx.x * 4 + (threadIdx.x >> 6);
    int lane = threadIdx.x & 63;
    if (v >= n) return;
    int beg = rowptr[v], end = rowptr[v + 1];
    int deg = end - beg;
    float adv = ad_[v];
    int sub = lane / C8;
    int c = lane % C8;
    float acc[8] = {0.f, 0.f, 0.f, 0.f, 0.f, 0.f, 0.f, 0.f};
    if (deg <= 64) {
        // one edge per lane: alpha/src held in registers, fetched via shuffle in pass 3
        int sreg = v;
        float e = -1e30f;
        if (lane < deg) {
            sreg = esrc[beg + lane];
            float t = as_[sreg] + adv;
            e = (t > 0.f) ? t : 0.2f * t;
        }
        float m = e;
#pragma unroll
        for (int o = 32; o > 0; o >>= 1) m = fmaxf(m, __shfl_xor(m, o));
        float ex = (lane < deg) ? __expf(e - m) : 0.f;
        float sum = ex;
#pragma unroll
        for (int o = 32; o > 0; o >>= 1) sum += __shfl_xor(sum, o);
        float alpha_r = ex / sum;
        for (int j0 = 0; j0 < deg; j0 += EPW) {
            int idx = j0 + sub;
            int cidx = (idx < deg) ? idx : 0;
            float alpha = __shfl(alpha_r, cidx);
            int s2 = __shfl(sreg, cidx);
            if (idx >= deg) alpha = 0.f;
            uint4 raw = ((const uint4*)(hl + (size_t)s2 * O))[c];
            acc[0] += alpha * __uint_as_float(raw.x << 16);
            acc[1] += alpha * __uint_as_float(raw.x & 0xffff0000u);
            acc[2] += alpha * __uint_as_float(raw.y << 16);
            acc[3] += alpha * __uint_as_float(raw.y & 0xffff0000u);
            acc[4] += alpha * __uint_as_float(raw.z << 16);
            acc[5] += alpha * __uint_as_float(raw.z & 0xffff0000u);
            acc[6] += alpha * __uint_as_float(raw.w << 16);
            acc[7] += alpha * __uint_as_float(raw.w & 0xffff0000u);
        }
    } else {
        // generic 3-pass path (deg > 64)
        float mymax = -1e30f;
        for (int j = beg + lane; j < end; j += 64) {
            float e = as_[esrc[j]] + adv;
            e = (e > 0.f) ? e : 0.2f * e;
            mymax = fmaxf(mymax, e);
        }
#pragma unroll
        for (int o = 32; o > 0; o >>= 1) mymax = fmaxf(mymax, __shfl_xor(mymax, o));
        float mysum = 0.f;
        for (int j = beg + lane; j < end; j += 64) {
            float e = as_[esrc[j]] + adv;
            e = (e > 0.f) ? e : 0.2f * e;
            mysum += __expf(e - mymax);
        }
#pragma unroll
        for (int o = 32; o > 0; o >>= 1) mysum += __shfl_xor(mysum, o);
        float invden = 1.f / mysum;
        for (int j0 = beg; j0 < end; j0 += EPW) {
            int j = j0 + sub;
            bool valid = j < end;
            int s = valid ? esrc[j] : v;
            float e = as_[s] + adv;
            e = (e > 0.f) ? e : 0.2f * e;
            float alpha = valid ? __expf(e - mymax) * invden : 0.f;
            uint4 raw = ((const uint4*)(hl + (size_t)s * O))[c];
            acc[0] += alpha * __uint_as_float(raw.x << 16);
            acc[1] += alpha * __uint_as_float(raw.x & 0xffff0000u);
            acc[2] += alpha * __uint_as_float(raw.y << 16);
            acc[3] += alpha * __uint_as_float(raw.y & 0xffff0000u);
            acc[4] += alpha * __uint_as_float(raw.z << 16);
            acc[5] += alpha * __uint_as_float(raw.z & 0xffff0000u);
            acc[6] += alpha * __uint_as_float(raw.w << 16);
            acc[7] += alpha * __uint_as_float(raw.w & 0xffff0000u);
        }
    }
#pragma unroll
    for (int o = C8; o < 64; o <<= 1)
#pragma unroll
        for (int k = 0; k < 8; k++) acc[k] += __shfl_xor(acc[k], o);
    if (sub == 0) {
        unsigned short ov[8];
#pragma unroll
        for (int k = 0; k < 8; k++) ov[k] = f2bf(fmaxf(acc[k] + bias[c * 8 + k], 0.f));
        uint4 packed;
        packed.x = (unsigned)ov[0] | ((unsigned)ov[1] << 16);
        packed.y = (unsigned)ov[2] | ((unsigned)ov[3] << 16);
        packed.z = (unsigned)ov[4] | ((unsigned)ov[5] << 16);
        packed.w = (unsigned)ov[6] | ((unsigned)ov[7] << 16);
        ((uint4*)(hout + (size_t)v * O))[c] = packed;
    }
}

// ---------------- fused mean-pool + linear + sigmoid: one block per graph ----------------
__global__ __launch_bounds__(256) void pool_final_kernel(
    const unsigned short* __restrict__ h, const int* __restrict__ start,
    const float* __restrict__ lw, const float* __restrict__ lb,
    float* __restrict__ out, int G) {
    __shared__ float red[8][33];
    int g = blockIdx.x;
    if (g >= G) return;
    int beg = start[g], end = start[g + 1];
    int tid = threadIdx.x;
    int nodeLane = tid >> 5, f = tid & 31;
    float acc = 0.f;
    for (int v = beg + nodeLane; v < end; v += 8)
        acc += bf2f(h[(size_t)v * 32 + f]);
    red[nodeLane][f] = acc;
    __syncthreads();
    if (tid < 32) {
        float s = 0.f;
#pragma unroll
        for (int i = 0; i < 8; i++) s += red[i][f];
        float inv = 1.f / fmaxf((float)(end - beg), 1.f);
        float val = s * inv * lw[f];
#pragma unroll
        for (int o = 16; o > 0; o >>= 1) val += __shfl_xor(val, o);
        if (f == 0) out[g] = 1.f / (1.f + __expf(-(val + lb[0])));
    }
}

extern "C" void kernel_launch(void* const* d_in, const int* in_sizes, int n_in,
                              void* d_out, int out_size, void* d_ws, size_t ws_size,
                              hipStream_t stream) {
    const float* x = (const float*)d_in[0];
    const int* ei = (const int*)d_in[1];
    const int* batch = (const int*)d_in[2];
    const float* w1 = (const float*)d_in[3];
    const float* b1 = (const float*)d_in[4];
    const float* w2 = (const float*)d_in[5];
    const float* b2 = (const float*)d_in[6];
    const float* w3 = (const float*)d_in[7];
    const float* b3 = (const float*)d_in[8];
    const float* gw[5];
    const float* gas[5];
    const float* gad[5];
    const float* gb[5];
    for (int l = 0; l < 5; l++) {
        gw[l] = (const float*)d_in[9 + l * 4 + 0];
        gas[l] = (const float*)d_in[9 + l * 4 + 1];
        gad[l] = (const float*)d_in[9 + l * 4 + 2];
        gb[l] = (const float*)d_in[9 + l * 4 + 3];
    }
    const float* lw = (const float*)d_in[29];
    const float* lb = (const float*)d_in[30];
    float* out = (float*)d_out;

    int N = in_sizes[0];
    int E = in_sizes[1] / 2;
    int G = out_size;
    int Etot = E + N;

    char* ws = (char*)d_ws;
    size_t off = 0;
    auto alloc = [&](size_t bytes) -> void* {
        void* p = ws + off;
        off = (off + bytes + 255) & ~(size_t)255;
        return p;
    };
    unsigned short* actA = (unsigned short*)alloc((size_t)N * 256 * 2);
    unsigned short* actB = (unsigned short*)alloc((size_t)N * 256 * 2);
    float* asb = (float*)alloc((size_t)N * 8);  // as | ad (written fully by gemm, no zeroing)
    float* adb = asb + N;
    int* deg = (int*)alloc((size_t)N * 4);
    int* rowptr = (int*)alloc((size_t)(N + 1) * 4);
    int* cursor = (int*)alloc((size_t)(N + 1) * 4);
    int* esrc = (int*)alloc((size_t)Etot * 4);
    int* bsums = (int*)alloc(4096);
    int* gstart = (int*)alloc((size_t)(G + 1) * 4);
    unsigned short* wbAll = (unsigned short*)alloc((size_t)83968 * 2);
    float* uAll = (float*)alloc((size_t)1280 * 4);
    const int woff[5] = {0, 8192, 40960, 73728, 81920};
    const int uoff[5] = {0, 64, 192, 448, 576};
    unsigned short* wb[5];
    for (int l = 0; l < 5; l++) wb[l] = wbAll + woff[l];
    (void)ws_size;
    (void)n_in;

    // 0. zero deg only
    hipMemsetAsync(deg, 0, (size_t)N * 4, stream);

    // 1. prelude: mlp(8 thr/node) + weight cast + graph starts + u vectors + degree hist
    int mlpB = (N + 31) / 32;
    int gsB = (G + 1 + 255) / 256;
    int histB = (Etot + 255) / 256;
    prelude_kernel<<<mlpB + F2BF_B + gsB + U_B + histB, 256, 0, stream>>>(
        x, w1, b1, w2, b2, w3, b3, actA, N, gw[0], gw[1], gw[2], gw[3], gw[4], wbAll,
        gas[0], gas[1], gas[2], gas[3], gas[4], gad[0], gad[1], gad[2], gad[3], gad[4], uAll,
        batch, gstart, G, ei + E, deg, E, mlpB, gsB);

    // 2. CSR scan + scatter
    int nb = (N + 1023) / 1024;
    scan_block_sums<<<nb, 256, 0, stream>>>(deg, bsums, N);
    scan_write<<<nb, 256, 0, stream>>>(deg, bsums, rowptr, cursor, N, nb);
    scatter_kernel<<<(Etot + 255) / 256, 256, 0, stream>>>(ei, ei + E, cursor, esrc, E, N);

    // 3. five GAT layers
    const int Ks[5] = {64, 128, 256, 128, 64};
    const int Os[5] = {128, 256, 128, 64, 32};
    int aggBlocks = (N + 3) / 4;
    int gx = (N + 127) / 128;
    for (int l = 0; l < 5; l++) {
        int K = Ks[l], O = Os[l];
        const float* us = uAll + uoff[l];
        const float* ud = uAll + 640 + uoff[l];
        if (O >= 64) {
            dim3 grid(gx, O / 64);
            gemm_mfma<64><<<grid, 256, 0, stream>>>(actA, wb[l], actB, us, ud, asb, adb, N, K, O);
        } else {
            dim3 grid(gx, 1);
            gemm_mfma<32><<<grid, 256, 0, stream>>>(actA, wb[l], actB, us, ud, asb, adb, N, K, O);
        }
        switch (O) {
            case 256:
                gat_aggregate<256><<<aggBlocks, 256, 0, stream>>>(actB, asb, adb, rowptr, esrc,
                                                                  gb[l], actA, N);
                break;
            case 128:
                gat_aggregate<128><<<aggBlocks, 256, 0, stream>>>(actB, asb, adb, rowptr, esrc,
                                                                  gb[l], actA, N);
                break;
            case 64:
                gat_aggregate<64><<<aggBlocks, 256, 0, stream>>>(actB, asb, adb, rowptr, esrc,
                                                                 gb[l], actA, N);
                break;
            default:
                gat_aggregate<32><<<aggBlocks, 256, 0, stream>>>(actB, asb, adb, rowptr, esrc,
                                                                 gb[l], actA, N);
                break;
        }
    }

    // 4. fused mean pool + linear + sigmoid
    pool_final_kernel<<<G, 256, 0, stream>>>(actA, gstart, lw, lb, out, G);
}

// Round 8
// 642.345 us; speedup vs baseline: 1.0178x; 1.0178x over previous
//
#include <hip/hip_runtime.h>
#include <math.h>

typedef __attribute__((ext_vector_type(8))) __bf16 bf16x8;
typedef __attribute__((ext_vector_type(4))) float f32x4;

__device__ inline unsigned short f2bf(float f) {  // RNE
    unsigned int i = __float_as_uint(f);
    unsigned int r = i + 0x7fffu + ((i >> 16) & 1u);
    return (unsigned short)(r >> 16);
}
__device__ inline float bf2f(unsigned short u) {
    return __uint_as_float(((unsigned int)u) << 16);
}

#define F2BF_B 329  // ceil(83968/256)
#define U_B 3       // ceil(640/256)

// ---------------- prelude: MLP (scalar-load weights) + weight-cast + gstart + u + hist ----
__global__ __launch_bounds__(256) void prelude_kernel(
    const float* __restrict__ x,
    const float* __restrict__ w1, const float* __restrict__ b1,
    const float* __restrict__ w2, const float* __restrict__ b2,
    const float* __restrict__ w3, const float* __restrict__ b3,
    unsigned short* __restrict__ h0, int n,
    const float* __restrict__ g0, const float* __restrict__ g1, const float* __restrict__ g2,
    const float* __restrict__ g3, const float* __restrict__ g4,
    unsigned short* __restrict__ wbAll,
    const float* __restrict__ s0, const float* __restrict__ s1, const float* __restrict__ s2,
    const float* __restrict__ s3, const float* __restrict__ s4,
    const float* __restrict__ d0, const float* __restrict__ d1, const float* __restrict__ d2,
    const float* __restrict__ d3, const float* __restrict__ d4,
    float* __restrict__ uAll,
    const int* __restrict__ batch, int* __restrict__ gstart, int G,
    const int* __restrict__ dst, int* __restrict__ deg, int E,
    int mlpB, int gsB) {
    int b = blockIdx.x;
    int tid = threadIdx.x;
    if (b < mlpB) {
        // 1 thread/node. Weight indices are wave-uniform -> s_load into SGPRs
        // (scalar pipe); hot loop is pure v_fma with one SGPR operand. No LDS.
        int node = b * 256 + tid;
        if (node >= n) return;
        float xv = x[node];
        float t1[16], t2[32];
#pragma unroll
        for (int i = 0; i < 16; i++) t1[i] = fmaxf(w1[i] * xv + b1[i], 0.f);
#pragma unroll
        for (int o = 0; o < 32; o++) {
            float a = b2[o];
#pragma unroll
            for (int i = 0; i < 16; i++) a += w2[o * 16 + i] * t1[i];
            t2[o] = fmaxf(a, 0.f);
        }
        uint4* gp = (uint4*)(h0 + (size_t)node * 64);
#pragma unroll
        for (int c = 0; c < 8; c++) {
            float av[8];
#pragma unroll
            for (int j = 0; j < 8; j++) {
                int o = c * 8 + j;
                float a = b3[o];
#pragma unroll
                for (int i = 0; i < 32; i++) a += w3[o * 32 + i] * t2[i];
                av[j] = fmaxf(a, 0.f);
            }
            unsigned wv[4];
#pragma unroll
            for (int p = 0; p < 4; p++)
                wv[p] = (unsigned)f2bf(av[2 * p]) | ((unsigned)f2bf(av[2 * p + 1]) << 16);
            gp[c] = make_uint4(wv[0], wv[1], wv[2], wv[3]);
        }
    } else if (b < mlpB + F2BF_B) {
        int i = (b - mlpB) * 256 + tid;
        // weight segment offsets: 0, 8192, 40960, 73728, 81920, end 83968
        float v;
        if (i < 8192) v = g0[i];
        else if (i < 40960) v = g1[i - 8192];
        else if (i < 73728) v = g2[i - 40960];
        else if (i < 81920) v = g3[i - 73728];
        else if (i < 83968) v = g4[i - 81920];
        else return;
        wbAll[i] = f2bf(v);
    } else if (b < mlpB + F2BF_B + gsB) {
        int g = (b - mlpB - F2BF_B) * 256 + tid;
        if (g > G) return;
        if (g == G) { gstart[G] = n; return; }
        int lo = 0, hi = n;
        while (lo < hi) {
            int mid = (lo + hi) >> 1;
            if (batch[mid] < g) lo = mid + 1;
            else hi = mid;
        }
        gstart[g] = lo;
    } else if (b < mlpB + F2BF_B + gsB + U_B) {
        // u_s[k] = sum_o W[o][k]*a_s[o]; layers packed at {0,64,192,448,576}, total 640
        int idx = (b - mlpB - F2BF_B - gsB) * 256 + tid;
        if (idx >= 640) return;
        int l, st, K, O;
        if (idx < 64) { l = 0; st = 0; K = 64; O = 128; }
        else if (idx < 192) { l = 1; st = 64; K = 128; O = 256; }
        else if (idx < 448) { l = 2; st = 192; K = 256; O = 128; }
        else if (idx < 576) { l = 3; st = 448; K = 128; O = 64; }
        else { l = 4; st = 576; K = 64; O = 32; }
        const float* W = (l == 0) ? g0 : (l == 1) ? g1 : (l == 2) ? g2 : (l == 3) ? g3 : g4;
        const float* as = (l == 0) ? s0 : (l == 1) ? s1 : (l == 2) ? s2 : (l == 3) ? s3 : s4;
        const float* ad = (l == 0) ? d0 : (l == 1) ? d1 : (l == 2) ? d2 : (l == 3) ? d3 : d4;
        int k = idx - st;
        float us = 0.f, ud = 0.f;
        for (int o = 0; o < O; o++) {
            float w = W[o * K + k];
            us += w * as[o];
            ud += w * ad[o];
        }
        uAll[idx] = us;
        uAll[640 + idx] = ud;
    } else {
        int e = (b - mlpB - F2BF_B - gsB - U_B) * 256 + tid;
        if (e >= E + n) return;
        int d = (e < E) ? dst[e] : (e - E);
        atomicAdd(&deg[d], 1);
    }
}

// ---------------- bf16 MFMA GEMM, 128xBN tile, BK=64 ----------------
// If us != null (layer 0 only): col0==0 blocks also emit as_[r] = A[r,:].us, ad_ likewise.
template <int BN>
__global__ __launch_bounds__(256) void gemm_mfma(
    const unsigned short* __restrict__ A, const unsigned short* __restrict__ Wb,
    unsigned short* __restrict__ Cb,
    const float* __restrict__ us, const float* __restrict__ ud,
    float* __restrict__ as_, float* __restrict__ ad_, int n, int K, int O) {
    constexpr int SN = BN / 32;
    __shared__ unsigned short As[128][72];  // +8 pad: frag reads <=2-way banks (free)
    __shared__ unsigned short Ws[BN][72];
    int tid = threadIdx.x;
    int row0 = blockIdx.x * 128, col0 = blockIdx.y * BN;
    int w = tid >> 6, lane = tid & 63;
    int wr = w >> 1, wc = w & 1;
    int quad = lane >> 4, l15 = lane & 15;
    f32x4 acc[4][SN];
#pragma unroll
    for (int mi = 0; mi < 4; mi++)
#pragma unroll
        for (int ni = 0; ni < SN; ni++) acc[mi][ni] = (f32x4){0.f, 0.f, 0.f, 0.f};
    float uacc_s = 0.f, uacc_d = 0.f;
    int urow = tid & 127, uhalf = tid >> 7;
    bool doU = (us != nullptr) && (col0 == 0);

    for (int k0 = 0; k0 < K; k0 += 64) {
#pragma unroll
        for (int i = tid; i < 1024; i += 256) {
            int r = i >> 3, c8 = i & 7;
            int gr = row0 + r;
            uint4 v = make_uint4(0u, 0u, 0u, 0u);
            if (gr < n) v = *(const uint4*)(A + (size_t)gr * K + k0 + c8 * 8);
            *(uint4*)&As[r][c8 * 8] = v;
        }
#pragma unroll
        for (int i = tid; i < BN * 8; i += 256) {
            int r = i >> 3, c8 = i & 7;
            uint4 v = *(const uint4*)(Wb + (size_t)(col0 + r) * K + k0 + c8 * 8);
            *(uint4*)&Ws[r][c8 * 8] = v;
        }
        __syncthreads();
        if (doU) {  // alpha-logit partial dots from the staged A tile (b128 reads)
            int kb = uhalf * 32;
#pragma unroll
            for (int q = 0; q < 4; q++) {
                uint4 rw = *(const uint4*)&As[urow][kb + q * 8];
                int kk = k0 + kb + q * 8;
                float a[8] = {__uint_as_float(rw.x << 16), __uint_as_float(rw.x & 0xffff0000u),
                              __uint_as_float(rw.y << 16), __uint_as_float(rw.y & 0xffff0000u),
                              __uint_as_float(rw.z << 16), __uint_as_float(rw.z & 0xffff0000u),
                              __uint_as_float(rw.w << 16), __uint_as_float(rw.w & 0xffff0000u)};
#pragma unroll
                for (int j = 0; j < 8; j++) {
                    uacc_s += a[j] * us[kk + j];
                    uacc_d += a[j] * ud[kk + j];
                }
            }
        }
#pragma unroll
        for (int kk = 0; kk < 64; kk += 32) {
            bf16x8 bfr[SN];
#pragma unroll
            for (int ni = 0; ni < SN; ni++)
                bfr[ni] = *(const bf16x8*)&Ws[wc * (BN / 2) + ni * 16 + l15][kk + quad * 8];
#pragma unroll
            for (int mi = 0; mi < 4; mi++) {
                bf16x8 afr = *(const bf16x8*)&As[wr * 64 + mi * 16 + l15][kk + quad * 8];
#pragma unroll
                for (int ni = 0; ni < SN; ni++)
                    acc[mi][ni] = __builtin_amdgcn_mfma_f32_16x16x32_bf16(afr, bfr[ni],
                                                                          acc[mi][ni], 0, 0, 0);
            }
        }
        __syncthreads();
    }
    if (doU) {
        float* red = (float*)&As[0][0];
        red[tid] = uacc_s;
        red[256 + tid] = uacc_d;
        __syncthreads();
        if (tid < 128) {
            int gr = row0 + tid;
            if (gr < n) {
                as_[gr] = red[tid] + red[tid + 128];
                ad_[gr] = red[256 + tid] + red[384 + tid];
            }
        }
    }
    int gc[SN];
#pragma unroll
    for (int ni = 0; ni < SN; ni++) gc[ni] = col0 + wc * (BN / 2) + ni * 16 + l15;
#pragma unroll
    for (int mi = 0; mi < 4; mi++) {
        int gm0 = row0 + wr * 64 + mi * 16 + quad * 4;
#pragma unroll
        for (int ni = 0; ni < SN; ni++) {
#pragma unroll
            for (int r = 0; r < 4; r++) {
                int gm = gm0 + r;
                if (gm < n) Cb[(size_t)gm * O + gc[ni]] = f2bf(acc[mi][ni][r]);
            }
        }
    }
}

// ---------------- scan: per-1024-chunk sums ----------------
__global__ void scan_block_sums(const int* __restrict__ deg, int* __restrict__ bsums, int n) {
    __shared__ int sdata[256];
    int tid = threadIdx.x;
    int base = blockIdx.x * 1024 + tid * 4;
    int s = 0;
    for (int i = 0; i < 4; i++) {
        int g = base + i;
        if (g < n) s += deg[g];
    }
    sdata[tid] = s;
    __syncthreads();
    for (int off = 128; off > 0; off >>= 1) {
        if (tid < off) sdata[tid] += sdata[tid + off];
        __syncthreads();
    }
    if (tid == 0) bsums[blockIdx.x] = sdata[0];
}

// ---------------- scan_write: inline bsums prefix (nb <= 256) + rowptr/cursor -------------
__global__ void scan_write(const int* __restrict__ deg, const int* __restrict__ bsums,
                           int* __restrict__ rowptr, int* __restrict__ cursor, int n, int nb) {
    __shared__ int sdata[256];
    int tid = threadIdx.x;
    sdata[tid] = (tid < blockIdx.x && tid < nb) ? bsums[tid] : 0;
    __syncthreads();
    for (int off = 128; off > 0; off >>= 1) {
        if (tid < off) sdata[tid] += sdata[tid + off];
        __syncthreads();
    }
    int base = sdata[0];
    __syncthreads();
    int gbase = blockIdx.x * 1024 + tid * 4;
    int v[4];
    int s = 0;
    for (int i = 0; i < 4; i++) {
        int g = gbase + i;
        v[i] = (g < n) ? deg[g] : 0;
        s += v[i];
    }
    sdata[tid] = s;
    __syncthreads();
    for (int off = 1; off < 256; off <<= 1) {
        int t = (tid >= off) ? sdata[tid - off] : 0;
        __syncthreads();
        sdata[tid] += t;
        __syncthreads();
    }
    int excl = sdata[tid] - s + base;
    for (int i = 0; i < 4; i++) {
        int g = gbase + i;
        if (g < n) { rowptr[g] = excl; cursor[g] = excl; }
        excl += v[i];
    }
    if (blockIdx.x == gridDim.x - 1 && tid == 255) rowptr[n] = base + sdata[255];
}

__global__ void scatter_kernel(const int* __restrict__ esrc_in, const int* __restrict__ edst_in,
                               int* __restrict__ cursor, int* __restrict__ esrc, int E, int n) {
    int e = blockIdx.x * 256 + threadIdx.x;
    if (e >= E + n) return;
    int s, d;
    if (e < E) { s = esrc_in[e]; d = edst_in[e]; }
    else { s = e - E; d = e - E; }
    int pos = atomicAdd(&cursor[d], 1);
    esrc[pos] = s;
}

// ---------------- GAT aggregation: one wave per dst node, bf16 features ----------------
// Epilogue also computes NEXT layer's alpha logits: as_out[v] = relu(h_out).us_next, etc.
// (as_/ad_ are ping-ponged across layers; usn==null for the last layer.)
template <int O>
__global__ __launch_bounds__(256) void gat_aggregate(
    const unsigned short* __restrict__ hl, const float* __restrict__ as_,
    const float* __restrict__ ad_, const int* __restrict__ rowptr,
    const int* __restrict__ esrc, const float* __restrict__ bias,
    unsigned short* __restrict__ hout, int n,
    const float* __restrict__ usn, const float* __restrict__ udn,
    float* __restrict__ as_out, float* __restrict__ ad_out) {
    constexpr int C8 = O / 8;
    constexpr int EPW = 64 / C8;
    int v = blockIdx.x * 4 + (threadIdx.x >> 6);
    int lane = threadIdx.x & 63;
    if (v >= n) return;
    int beg = rowptr[v], end = rowptr[v + 1];
    int deg = end - beg;
    float adv = ad_[v];
    int sub = lane / C8;
    int c = lane % C8;
    float acc[8] = {0.f, 0.f, 0.f, 0.f, 0.f, 0.f, 0.f, 0.f};
    if (deg <= 64) {
        // one edge per lane: alpha/src held in registers, fetched via shuffle in pass 3
        int sreg = v;
        float e = -1e30f;
        if (lane < deg) {
            sreg = esrc[beg + lane];
            float t = as_[sreg] + adv;
            e = (t > 0.f) ? t : 0.2f * t;
        }
        float m = e;
#pragma unroll
        for (int o = 32; o > 0; o >>= 1) m = fmaxf(m, __shfl_xor(m, o));
        float ex = (lane < deg) ? __expf(e - m) : 0.f;
        float sum = ex;
#pragma unroll
        for (int o = 32; o > 0; o >>= 1) sum += __shfl_xor(sum, o);
        float alpha_r = ex / sum;
        for (int j0 = 0; j0 < deg; j0 += EPW) {
            int idx = j0 + sub;
            int cidx = (idx < deg) ? idx : 0;
            float alpha = __shfl(alpha_r, cidx);
            int s2 = __shfl(sreg, cidx);
            if (idx >= deg) alpha = 0.f;
            uint4 raw = ((const uint4*)(hl + (size_t)s2 * O))[c];
            acc[0] += alpha * __uint_as_float(raw.x << 16);
            acc[1] += alpha * __uint_as_float(raw.x & 0xffff0000u);
            acc[2] += alpha * __uint_as_float(raw.y << 16);
            acc[3] += alpha * __uint_as_float(raw.y & 0xffff0000u);
            acc[4] += alpha * __uint_as_float(raw.z << 16);
            acc[5] += alpha * __uint_as_float(raw.z & 0xffff0000u);
            acc[6] += alpha * __uint_as_float(raw.w << 16);
            acc[7] += alpha * __uint_as_float(raw.w & 0xffff0000u);
        }
    } else {
        // generic 3-pass path (deg > 64)
        float mymax = -1e30f;
        for (int j = beg + lane; j < end; j += 64) {
            float e = as_[esrc[j]] + adv;
            e = (e > 0.f) ? e : 0.2f * e;
            mymax = fmaxf(mymax, e);
        }
#pragma unroll
        for (int o = 32; o > 0; o >>= 1) mymax = fmaxf(mymax, __shfl_xor(mymax, o));
        float mysum = 0.f;
        for (int j = beg + lane; j < end; j += 64) {
            float e = as_[esrc[j]] + adv;
            e = (e > 0.f) ? e : 0.2f * e;
            mysum += __expf(e - mymax);
        }
#pragma unroll
        for (int o = 32; o > 0; o >>= 1) mysum += __shfl_xor(mysum, o);
        float invden = 1.f / mysum;
        for (int j0 = beg; j0 < end; j0 += EPW) {
            int j = j0 + sub;
            bool valid = j < end;
            int s = valid ? esrc[j] : v;
            float e = as_[s] + adv;
            e = (e > 0.f) ? e : 0.2f * e;
            float alpha = valid ? __expf(e - mymax) * invden : 0.f;
            uint4 raw = ((const uint4*)(hl + (size_t)s * O))[c];
            acc[0] += alpha * __uint_as_float(raw.x << 16);
            acc[1] += alpha * __uint_as_float(raw.x & 0xffff0000u);
            acc[2] += alpha * __uint_as_float(raw.y << 16);
            acc[3] += alpha * __uint_as_float(raw.y & 0xffff0000u);
            acc[4] += alpha * __uint_as_float(raw.z << 16);
            acc[5] += alpha * __uint_as_float(raw.z & 0xffff0000u);
            acc[6] += alpha * __uint_as_float(raw.w << 16);
            acc[7] += alpha * __uint_as_float(raw.w & 0xffff0000u);
        }
    }
#pragma unroll
    for (int o = C8; o < 64; o <<= 1)
#pragma unroll
        for (int k = 0; k < 8; k++) acc[k] += __shfl_xor(acc[k], o);
    if (sub == 0) {
        float val[8];
#pragma unroll
        for (int k = 0; k < 8; k++) val[k] = fmaxf(acc[k] + bias[c * 8 + k], 0.f);
        if (usn) {  // next layer's alpha logits (fp32, pre-rounding)
            float ps = 0.f, pd = 0.f;
#pragma unroll
            for (int k = 0; k < 8; k++) {
                ps += val[k] * usn[c * 8 + k];
                pd += val[k] * udn[c * 8 + k];
            }
#pragma unroll
            for (int m = 1; m < C8; m <<= 1) {
                ps += __shfl_xor(ps, m);
                pd += __shfl_xor(pd, m);
            }
            if (lane == 0) {
                as_out[v] = ps;
                ad_out[v] = pd;
            }
        }
        unsigned short ov[8];
#pragma unroll
        for (int k = 0; k < 8; k++) ov[k] = f2bf(val[k]);
        uint4 packed;
        packed.x = (unsigned)ov[0] | ((unsigned)ov[1] << 16);
        packed.y = (unsigned)ov[2] | ((unsigned)ov[3] << 16);
        packed.z = (unsigned)ov[4] | ((unsigned)ov[5] << 16);
        packed.w = (unsigned)ov[6] | ((unsigned)ov[7] << 16);
        ((uint4*)(hout + (size_t)v * O))[c] = packed;
    }
}

// ---------------- fused mean-pool + linear + sigmoid: one block per graph ----------------
__global__ __launch_bounds__(256) void pool_final_kernel(
    const unsigned short* __restrict__ h, const int* __restrict__ start,
    const float* __restrict__ lw, const float* __restrict__ lb,
    float* __restrict__ out, int G) {
    __shared__ float red[8][33];
    int g = blockIdx.x;
    if (g >= G) return;
    int beg = start[g], end = start[g + 1];
    int tid = threadIdx.x;
    int nodeLane = tid >> 5, f = tid & 31;
    float acc = 0.f;
    for (int v = beg + nodeLane; v < end; v += 8)
        acc += bf2f(h[(size_t)v * 32 + f]);
    red[nodeLane][f] = acc;
    __syncthreads();
    if (tid < 32) {
        float s = 0.f;
#pragma unroll
        for (int i = 0; i < 8; i++) s += red[i][f];
        float inv = 1.f / fmaxf((float)(end - beg), 1.f);
        float val = s * inv * lw[f];
#pragma unroll
        for (int o = 16; o > 0; o >>= 1) val += __shfl_xor(val, o);
        if (f == 0) out[g] = 1.f / (1.f + __expf(-(val + lb[0])));
    }
}

extern "C" void kernel_launch(void* const* d_in, const int* in_sizes, int n_in,
                              void* d_out, int out_size, void* d_ws, size_t ws_size,
                              hipStream_t stream) {
    const float* x = (const float*)d_in[0];
    const int* ei = (const int*)d_in[1];
    const int* batch = (const int*)d_in[2];
    const float* w1 = (const float*)d_in[3];
    const float* b1 = (const float*)d_in[4];
    const float* w2 = (const float*)d_in[5];
    const float* b2 = (const float*)d_in[6];
    const float* w3 = (const float*)d_in[7];
    const float* b3 = (const float*)d_in[8];
    const float* gw[5];
    const float* gas[5];
    const float* gad[5];
    const float* gb[5];
    for (int l = 0; l < 5; l++) {
        gw[l] = (const float*)d_in[9 + l * 4 + 0];
        gas[l] = (const float*)d_in[9 + l * 4 + 1];
        gad[l] = (const float*)d_in[9 + l * 4 + 2];
        gb[l] = (const float*)d_in[9 + l * 4 + 3];
    }
    const float* lw = (const float*)d_in[29];
    const float* lb = (const float*)d_in[30];
    float* out = (float*)d_out;

    int N = in_sizes[0];
    int E = in_sizes[1] / 2;
    int G = out_size;
    int Etot = E + N;

    char* ws = (char*)d_ws;
    size_t off = 0;
    auto alloc = [&](size_t bytes) -> void* {
        void* p = ws + off;
        off = (off + bytes + 255) & ~(size_t)255;
        return p;
    };
    unsigned short* actA = (unsigned short*)alloc((size_t)N * 256 * 2);
    unsigned short* actB = (unsigned short*)alloc((size_t)N * 256 * 2);
    float* logit0 = (float*)alloc((size_t)N * 8);  // as|ad ping
    float* logit1 = (float*)alloc((size_t)N * 8);  // as|ad pong
    int* deg = (int*)alloc((size_t)N * 4);
    int* rowptr = (int*)alloc((size_t)(N + 1) * 4);
    int* cursor = (int*)alloc((size_t)(N + 1) * 4);
    int* esrc = (int*)alloc((size_t)Etot * 4);
    int* bsums = (int*)alloc(4096);
    int* gstart = (int*)alloc((size_t)(G + 1) * 4);
    unsigned short* wbAll = (unsigned short*)alloc((size_t)83968 * 2);
    float* uAll = (float*)alloc((size_t)1280 * 4);
    const int woff[5] = {0, 8192, 40960, 73728, 81920};
    const int uoff[5] = {0, 64, 192, 448, 576};
    unsigned short* wb[5];
    for (int l = 0; l < 5; l++) wb[l] = wbAll + woff[l];
    (void)ws_size;
    (void)n_in;

    // 0. zero deg only
    hipMemsetAsync(deg, 0, (size_t)N * 4, stream);

    // 1. prelude
    int mlpB = (N + 255) / 256;
    int gsB = (G + 1 + 255) / 256;
    int histB = (Etot + 255) / 256;
    prelude_kernel<<<mlpB + F2BF_B + gsB + U_B + histB, 256, 0, stream>>>(
        x, w1, b1, w2, b2, w3, b3, actA, N, gw[0], gw[1], gw[2], gw[3], gw[4], wbAll,
        gas[0], gas[1], gas[2], gas[3], gas[4], gad[0], gad[1], gad[2], gad[3], gad[4], uAll,
        batch, gstart, G, ei + E, deg, E, mlpB, gsB);

    // 2. CSR scan + scatter
    int nb = (N + 1023) / 1024;
    scan_block_sums<<<nb, 256, 0, stream>>>(deg, bsums, N);
    scan_write<<<nb, 256, 0, stream>>>(deg, bsums, rowptr, cursor, N, nb);
    scatter_kernel<<<(Etot + 255) / 256, 256, 0, stream>>>(ei, ei + E, cursor, esrc, E, N);

    // 3. five GAT layers; layer-l logits live in buf[l&1]; gemm0 produces layer-0 logits,
    //    each aggregate produces the next layer's logits from its in-register output.
    const int Ks[5] = {64, 128, 256, 128, 64};
    const int Os[5] = {128, 256, 128, 64, 32};
    int aggBlocks = (N + 3) / 4;
    int gx = (N + 127) / 128;
    for (int l = 0; l < 5; l++) {
        int K = Ks[l], O = Os[l];
        float* lg = (l & 1) ? logit1 : logit0;      // this layer's logits
        float* lgn = (l & 1) ? logit0 : logit1;     // next layer's logits
        const float* gus = (l == 0) ? uAll + uoff[0] : nullptr;
        const float* gud = (l == 0) ? uAll + 640 + uoff[0] : nullptr;
        const float* usn = (l < 4) ? uAll + uoff[l + 1] : nullptr;
        const float* udn = (l < 4) ? uAll + 640 + uoff[l + 1] : nullptr;
        if (O >= 64) {
            dim3 grid(gx, O / 64);
            gemm_mfma<64><<<grid, 256, 0, stream>>>(actA, wb[l], actB, gus, gud, lg, lg + N, N,
                                                    K, O);
        } else {
            dim3 grid(gx, 1);
            gemm_mfma<32><<<grid, 256, 0, stream>>>(actA, wb[l], actB, gus, gud, lg, lg + N, N,
                                                    K, O);
        }
        switch (O) {
            case 256:
                gat_aggregate<256><<<aggBlocks, 256, 0, stream>>>(
                    actB, lg, lg + N, rowptr, esrc, gb[l], actA, N, usn, udn, lgn, lgn + N);
                break;
            case 128:
                gat_aggregate<128><<<aggBlocks, 256, 0, stream>>>(
                    actB, lg, lg + N, rowptr, esrc, gb[l], actA, N, usn, udn, lgn, lgn + N);
                break;
            case 64:
                gat_aggregate<64><<<aggBlocks, 256, 0, stream>>>(
                    actB, lg, lg + N, rowptr, esrc, gb[l], actA, N, usn, udn, lgn, lgn + N);
                break;
            default:
                gat_aggregate<32><<<aggBlocks, 256, 0, stream>>>(
                    actB, lg, lg + N, rowptr, esrc, gb[l], actA, N, usn, udn, lgn, lgn + N);
                break;
        }
    }

    // 4. fused mean pool + linear + sigmoid
    pool_final_kernel<<<G, 256, 0, stream>>>(actA, gstart, lw, lb, out, G);
}

// Round 9
// 640.909 us; speedup vs baseline: 1.0201x; 1.0022x over previous
//
#include <hip/hip_runtime.h>
#include <math.h>

typedef __attribute__((ext_vector_type(8))) __bf16 bf16x8;
typedef __attribute__((ext_vector_type(4))) float f32x4;

__device__ inline unsigned short f2bf(float f) {  // RNE
    unsigned int i = __float_as_uint(f);
    unsigned int r = i + 0x7fffu + ((i >> 16) & 1u);
    return (unsigned short)(r >> 16);
}
__device__ inline float bf2f(unsigned short u) {
    return __uint_as_float(((unsigned int)u) << 16);
}

// broadcast lane l's copy of v to all lanes (lane index compile-time after unroll)
#define RL(v, l) __uint_as_float(__builtin_amdgcn_readlane(__float_as_uint(v), (l)))

#define F2BF_B 329  // ceil(83968/256)
#define U_B 3       // ceil(640/256)

// ---------------- prelude: MLP (VGPR weights + readlane) + cast + gstart + u + hist ------
__global__ __launch_bounds__(256) void prelude_kernel(
    const float* __restrict__ x,
    const float* __restrict__ w1, const float* __restrict__ b1,
    const float* __restrict__ w2, const float* __restrict__ b2,
    const float* __restrict__ w3, const float* __restrict__ b3,
    unsigned short* __restrict__ h0, int n,
    const float* __restrict__ g0, const float* __restrict__ g1, const float* __restrict__ g2,
    const float* __restrict__ g3, const float* __restrict__ g4,
    unsigned short* __restrict__ wbAll,
    const float* __restrict__ s0, const float* __restrict__ s1, const float* __restrict__ s2,
    const float* __restrict__ s3, const float* __restrict__ s4,
    const float* __restrict__ d0, const float* __restrict__ d1, const float* __restrict__ d2,
    const float* __restrict__ d3, const float* __restrict__ d4,
    float* __restrict__ uAll,
    const int* __restrict__ batch, int* __restrict__ gstart, int G,
    const int* __restrict__ dst, int* __restrict__ deg, int E,
    int mlpB, int gsB) {
    int b = blockIdx.x;
    int tid = threadIdx.x;
    if (b < mlpB) {
        // Weights live in VGPRs (coalesced load once per wave); hot loop is
        // v_readlane + v_fma only — no LDS, no scalar-mem in the chain.
        // NOTE: no early return before the loads: tail lanes must still
        // populate VGPRs that readlane sources.
        int lane = tid & 63;
        int node = b * 256 + tid;
        float vw1 = w1[lane & 15];
        float vb1 = b1[lane & 15];
        float vb2 = b2[lane & 31];
        float vb3 = b3[lane];
        float vw2[8], vw3[32];
#pragma unroll
        for (int j = 0; j < 8; j++) vw2[j] = w2[j * 64 + lane];
#pragma unroll
        for (int j = 0; j < 32; j++) vw3[j] = w3[j * 64 + lane];
        float xv = (node < n) ? x[node] : 0.f;
        float t1[16], t2[32];
#pragma unroll
        for (int i = 0; i < 16; i++) t1[i] = fmaxf(RL(vw1, i) * xv + RL(vb1, i), 0.f);
#pragma unroll
        for (int o = 0; o < 32; o++) {
            float a = RL(vb2, o);
#pragma unroll
            for (int i = 0; i < 16; i++) {
                int flat = o * 16 + i;
                a += RL(vw2[flat >> 6], flat & 63) * t1[i];
            }
            t2[o] = fmaxf(a, 0.f);
        }
        if (node >= n) return;
        uint4* gp = (uint4*)(h0 + (size_t)node * 64);
#pragma unroll
        for (int c = 0; c < 8; c++) {
            float av[8];
#pragma unroll
            for (int j = 0; j < 8; j++) {
                int o = c * 8 + j;
                float a = RL(vb3, o);
#pragma unroll
                for (int i = 0; i < 32; i++) {
                    int flat = o * 32 + i;
                    a += RL(vw3[flat >> 6], flat & 63) * t2[i];
                }
                av[j] = fmaxf(a, 0.f);
            }
            unsigned wv[4];
#pragma unroll
            for (int p = 0; p < 4; p++)
                wv[p] = (unsigned)f2bf(av[2 * p]) | ((unsigned)f2bf(av[2 * p + 1]) << 16);
            gp[c] = make_uint4(wv[0], wv[1], wv[2], wv[3]);
        }
    } else if (b < mlpB + F2BF_B) {
        int i = (b - mlpB) * 256 + tid;
        // weight segment offsets: 0, 8192, 40960, 73728, 81920, end 83968
        float v;
        if (i < 8192) v = g0[i];
        else if (i < 40960) v = g1[i - 8192];
        else if (i < 73728) v = g2[i - 40960];
        else if (i < 81920) v = g3[i - 73728];
        else if (i < 83968) v = g4[i - 81920];
        else return;
        wbAll[i] = f2bf(v);
    } else if (b < mlpB + F2BF_B + gsB) {
        int g = (b - mlpB - F2BF_B) * 256 + tid;
        if (g > G) return;
        if (g == G) { gstart[G] = n; return; }
        int lo = 0, hi = n;
        while (lo < hi) {
            int mid = (lo + hi) >> 1;
            if (batch[mid] < g) lo = mid + 1;
            else hi = mid;
        }
        gstart[g] = lo;
    } else if (b < mlpB + F2BF_B + gsB + U_B) {
        // u_s[k] = sum_o W[o][k]*a_s[o]; layers packed at {0,64,192,448,576}, total 640
        int idx = (b - mlpB - F2BF_B - gsB) * 256 + tid;
        if (idx >= 640) return;
        int l, st, K, O;
        if (idx < 64) { l = 0; st = 0; K = 64; O = 128; }
        else if (idx < 192) { l = 1; st = 64; K = 128; O = 256; }
        else if (idx < 448) { l = 2; st = 192; K = 256; O = 128; }
        else if (idx < 576) { l = 3; st = 448; K = 128; O = 64; }
        else { l = 4; st = 576; K = 64; O = 32; }
        const float* W = (l == 0) ? g0 : (l == 1) ? g1 : (l == 2) ? g2 : (l == 3) ? g3 : g4;
        const float* as = (l == 0) ? s0 : (l == 1) ? s1 : (l == 2) ? s2 : (l == 3) ? s3 : s4;
        const float* ad = (l == 0) ? d0 : (l == 1) ? d1 : (l == 2) ? d2 : (l == 3) ? d3 : d4;
        int k = idx - st;
        float us = 0.f, ud = 0.f;
        for (int o = 0; o < O; o++) {
            float w = W[o * K + k];
            us += w * as[o];
            ud += w * ad[o];
        }
        uAll[idx] = us;
        uAll[640 + idx] = ud;
    } else {
        int e = (b - mlpB - F2BF_B - gsB - U_B) * 256 + tid;
        if (e >= E + n) return;
        int d = (e < E) ? dst[e] : (e - E);
        atomicAdd(&deg[d], 1);
    }
}

// ---------------- bf16 MFMA GEMM, 128xBN tile, BK=64 ----------------
// If us != null (layer 0 only): col0==0 blocks also emit as_[r] = A[r,:].us, ad_ likewise.
template <int BN>
__global__ __launch_bounds__(256) void gemm_mfma(
    const unsigned short* __restrict__ A, const unsigned short* __restrict__ Wb,
    unsigned short* __restrict__ Cb,
    const float* __restrict__ us, const float* __restrict__ ud,
    float* __restrict__ as_, float* __restrict__ ad_, int n, int K, int O) {
    constexpr int SN = BN / 32;
    __shared__ unsigned short As[128][72];  // +8 pad: frag reads <=2-way banks (free)
    __shared__ unsigned short Ws[BN][72];
    int tid = threadIdx.x;
    int row0 = blockIdx.x * 128, col0 = blockIdx.y * BN;
    int w = tid >> 6, lane = tid & 63;
    int wr = w >> 1, wc = w & 1;
    int quad = lane >> 4, l15 = lane & 15;
    f32x4 acc[4][SN];
#pragma unroll
    for (int mi = 0; mi < 4; mi++)
#pragma unroll
        for (int ni = 0; ni < SN; ni++) acc[mi][ni] = (f32x4){0.f, 0.f, 0.f, 0.f};
    float uacc_s = 0.f, uacc_d = 0.f;
    int urow = tid & 127, uhalf = tid >> 7;
    bool doU = (us != nullptr) && (col0 == 0);

    for (int k0 = 0; k0 < K; k0 += 64) {
#pragma unroll
        for (int i = tid; i < 1024; i += 256) {
            int r = i >> 3, c8 = i & 7;
            int gr = row0 + r;
            uint4 v = make_uint4(0u, 0u, 0u, 0u);
            if (gr < n) v = *(const uint4*)(A + (size_t)gr * K + k0 + c8 * 8);
            *(uint4*)&As[r][c8 * 8] = v;
        }
#pragma unroll
        for (int i = tid; i < BN * 8; i += 256) {
            int r = i >> 3, c8 = i & 7;
            uint4 v = *(const uint4*)(Wb + (size_t)(col0 + r) * K + k0 + c8 * 8);
            *(uint4*)&Ws[r][c8 * 8] = v;
        }
        __syncthreads();
        if (doU) {  // alpha-logit partial dots from the staged A tile (b128 reads)
            int kb = uhalf * 32;
#pragma unroll
            for (int q = 0; q < 4; q++) {
                uint4 rw = *(const uint4*)&As[urow][kb + q * 8];
                int kk = k0 + kb + q * 8;
                float a[8] = {__uint_as_float(rw.x << 16), __uint_as_float(rw.x & 0xffff0000u),
                              __uint_as_float(rw.y << 16), __uint_as_float(rw.y & 0xffff0000u),
                              __uint_as_float(rw.z << 16), __uint_as_float(rw.z & 0xffff0000u),
                              __uint_as_float(rw.w << 16), __uint_as_float(rw.w & 0xffff0000u)};
#pragma unroll
                for (int j = 0; j < 8; j++) {
                    uacc_s += a[j] * us[kk + j];
                    uacc_d += a[j] * ud[kk + j];
                }
            }
        }
#pragma unroll
        for (int kk = 0; kk < 64; kk += 32) {
            bf16x8 bfr[SN];
#pragma unroll
            for (int ni = 0; ni < SN; ni++)
                bfr[ni] = *(const bf16x8*)&Ws[wc * (BN / 2) + ni * 16 + l15][kk + quad * 8];
#pragma unroll
            for (int mi = 0; mi < 4; mi++) {
                bf16x8 afr = *(const bf16x8*)&As[wr * 64 + mi * 16 + l15][kk + quad * 8];
#pragma unroll
                for (int ni = 0; ni < SN; ni++)
                    acc[mi][ni] = __builtin_amdgcn_mfma_f32_16x16x32_bf16(afr, bfr[ni],
                                                                          acc[mi][ni], 0, 0, 0);
            }
        }
        __syncthreads();
    }
    if (doU) {
        float* red = (float*)&As[0][0];
        red[tid] = uacc_s;
        red[256 + tid] = uacc_d;
        __syncthreads();
        if (tid < 128) {
            int gr = row0 + tid;
            if (gr < n) {
                as_[gr] = red[tid] + red[tid + 128];
                ad_[gr] = red[256 + tid] + red[384 + tid];
            }
        }
    }
    int gc[SN];
#pragma unroll
    for (int ni = 0; ni < SN; ni++) gc[ni] = col0 + wc * (BN / 2) + ni * 16 + l15;
#pragma unroll
    for (int mi = 0; mi < 4; mi++) {
        int gm0 = row0 + wr * 64 + mi * 16 + quad * 4;
#pragma unroll
        for (int ni = 0; ni < SN; ni++) {
#pragma unroll
            for (int r = 0; r < 4; r++) {
                int gm = gm0 + r;
                if (gm < n) Cb[(size_t)gm * O + gc[ni]] = f2bf(acc[mi][ni][r]);
            }
        }
    }
}

// ---------------- scan: per-1024-chunk sums ----------------
__global__ void scan_block_sums(const int* __restrict__ deg, int* __restrict__ bsums, int n) {
    __shared__ int sdata[256];
    int tid = threadIdx.x;
    int base = blockIdx.x * 1024 + tid * 4;
    int s = 0;
    for (int i = 0; i < 4; i++) {
        int g = base + i;
        if (g < n) s += deg[g];
    }
    sdata[tid] = s;
    __syncthreads();
    for (int off = 128; off > 0; off >>= 1) {
        if (tid < off) sdata[tid] += sdata[tid + off];
        __syncthreads();
    }
    if (tid == 0) bsums[blockIdx.x] = sdata[0];
}

// ---------------- scan_write: inline bsums prefix (nb <= 256) + rowptr/cursor -------------
__global__ void scan_write(const int* __restrict__ deg, const int* __restrict__ bsums,
                           int* __restrict__ rowptr, int* __restrict__ cursor, int n, int nb) {
    __shared__ int sdata[256];
    int tid = threadIdx.x;
    sdata[tid] = (tid < blockIdx.x && tid < nb) ? bsums[tid] : 0;
    __syncthreads();
    for (int off = 128; off > 0; off >>= 1) {
        if (tid < off) sdata[tid] += sdata[tid + off];
        __syncthreads();
    }
    int base = sdata[0];
    __syncthreads();
    int gbase = blockIdx.x * 1024 + tid * 4;
    int v[4];
    int s = 0;
    for (int i = 0; i < 4; i++) {
        int g = gbase + i;
        v[i] = (g < n) ? deg[g] : 0;
        s += v[i];
    }
    sdata[tid] = s;
    __syncthreads();
    for (int off = 1; off < 256; off <<= 1) {
        int t = (tid >= off) ? sdata[tid - off] : 0;
        __syncthreads();
        sdata[tid] += t;
        __syncthreads();
    }
    int excl = sdata[tid] - s + base;
    for (int i = 0; i < 4; i++) {
        int g = gbase + i;
        if (g < n) { rowptr[g] = excl; cursor[g] = excl; }
        excl += v[i];
    }
    if (blockIdx.x == gridDim.x - 1 && tid == 255) rowptr[n] = base + sdata[255];
}

__global__ void scatter_kernel(const int* __restrict__ esrc_in, const int* __restrict__ edst_in,
                               int* __restrict__ cursor, int* __restrict__ esrc, int E, int n) {
    int e = blockIdx.x * 256 + threadIdx.x;
    if (e >= E + n) return;
    int s, d;
    if (e < E) { s = esrc_in[e]; d = edst_in[e]; }
    else { s = e - E; d = e - E; }
    int pos = atomicAdd(&cursor[d], 1);
    esrc[pos] = s;
}

// ---------------- GAT aggregation: one wave per dst node, bf16 features ----------------
// Epilogue also computes NEXT layer's alpha logits: as_out[v] = relu(h_out).us_next, etc.
template <int O>
__global__ __launch_bounds__(256) void gat_aggregate(
    const unsigned short* __restrict__ hl, const float* __restrict__ as_,
    const float* __restrict__ ad_, const int* __restrict__ rowptr,
    const int* __restrict__ esrc, const float* __restrict__ bias,
    unsigned short* __restrict__ hout, int n,
    const float* __restrict__ usn, const float* __restrict__ udn,
    float* __restrict__ as_out, float* __restrict__ ad_out) {
    constexpr int C8 = O / 8;
    constexpr int EPW = 64 / C8;
    int v = blockIdx.x * 4 + (threadIdx.x >> 6);
    int lane = threadIdx.x & 63;
    if (v >= n) return;
    int beg = rowptr[v], end = rowptr[v + 1];
    int deg = end - beg;
    float adv = ad_[v];
    int sub = lane / C8;
    int c = lane % C8;
    float acc[8] = {0.f, 0.f, 0.f, 0.f, 0.f, 0.f, 0.f, 0.f};
    if (deg <= 64) {
        // one edge per lane: alpha/src held in registers, fetched via shuffle in pass 3
        int sreg = v;
        float e = -1e30f;
        if (lane < deg) {
            sreg = esrc[beg + lane];
            float t = as_[sreg] + adv;
            e = (t > 0.f) ? t : 0.2f * t;
        }
        float m = e;
#pragma unroll
        for (int o = 32; o > 0; o >>= 1) m = fmaxf(m, __shfl_xor(m, o));
        float ex = (lane < deg) ? __expf(e - m) : 0.f;
        float sum = ex;
#pragma unroll
        for (int o = 32; o > 0; o >>= 1) sum += __shfl_xor(sum, o);
        float alpha_r = ex / sum;
        for (int j0 = 0; j0 < deg; j0 += EPW) {
            int idx = j0 + sub;
            int cidx = (idx < deg) ? idx : 0;
            float alpha = __shfl(alpha_r, cidx);
            int s2 = __shfl(sreg, cidx);
            if (idx >= deg) alpha = 0.f;
            uint4 raw = ((const uint4*)(hl + (size_t)s2 * O))[c];
            acc[0] += alpha * __uint_as_float(raw.x << 16);
            acc[1] += alpha * __uint_as_float(raw.x & 0xffff0000u);
            acc[2] += alpha * __uint_as_float(raw.y << 16);
            acc[3] += alpha * __uint_as_float(raw.y & 0xffff0000u);
            acc[4] += alpha * __uint_as_float(raw.z << 16);
            acc[5] += alpha * __uint_as_float(raw.z & 0xffff0000u);
            acc[6] += alpha * __uint_as_float(raw.w << 16);
            acc[7] += alpha * __uint_as_float(raw.w & 0xffff0000u);
        }
    } else {
        // generic 3-pass path (deg > 64)
        float mymax = -1e30f;
        for (int j = beg + lane; j < end; j += 64) {
            float e = as_[esrc[j]] + adv;
            e = (e > 0.f) ? e : 0.2f * e;
            mymax = fmaxf(mymax, e);
        }
#pragma unroll
        for (int o = 32; o > 0; o >>= 1) mymax = fmaxf(mymax, __shfl_xor(mymax, o));
        float mysum = 0.f;
        for (int j = beg + lane; j < end; j += 64) {
            float e = as_[esrc[j]] + adv;
            e = (e > 0.f) ? e : 0.2f * e;
            mysum += __expf(e - mymax);
        }
#pragma unroll
        for (int o = 32; o > 0; o >>= 1) mysum += __shfl_xor(mysum, o);
        float invden = 1.f / mysum;
        for (int j0 = beg; j0 < end; j0 += EPW) {
            int j = j0 + sub;
            bool valid = j < end;
            int s = valid ? esrc[j] : v;
            float e = as_[s] + adv;
            e = (e > 0.f) ? e : 0.2f * e;
            float alpha = valid ? __expf(e - mymax) * invden : 0.f;
            uint4 raw = ((const uint4*)(hl + (size_t)s * O))[c];
            acc[0] += alpha * __uint_as_float(raw.x << 16);
            acc[1] += alpha * __uint_as_float(raw.x & 0xffff0000u);
            acc[2] += alpha * __uint_as_float(raw.y << 16);
            acc[3] += alpha * __uint_as_float(raw.y & 0xffff0000u);
            acc[4] += alpha * __uint_as_float(raw.z << 16);
            acc[5] += alpha * __uint_as_float(raw.z & 0xffff0000u);
            acc[6] += alpha * __uint_as_float(raw.w << 16);
            acc[7] += alpha * __uint_as_float(raw.w & 0xffff0000u);
        }
    }
#pragma unroll
    for (int o = C8; o < 64; o <<= 1)
#pragma unroll
        for (int k = 0; k < 8; k++) acc[k] += __shfl_xor(acc[k], o);
    if (sub == 0) {
        float val[8];
#pragma unroll
        for (int k = 0; k < 8; k++) val[k] = fmaxf(acc[k] + bias[c * 8 + k], 0.f);
        if (usn) {  // next layer's alpha logits (fp32, pre-rounding)
            float ps = 0.f, pd = 0.f;
#pragma unroll
            for (int k = 0; k < 8; k++) {
                ps += val[k] * usn[c * 8 + k];
                pd += val[k] * udn[c * 8 + k];
            }
#pragma unroll
            for (int m = 1; m < C8; m <<= 1) {
                ps += __shfl_xor(ps, m);
                pd += __shfl_xor(pd, m);
            }
            if (lane == 0) {
                as_out[v] = ps;
                ad_out[v] = pd;
            }
        }
        unsigned short ov[8];
#pragma unroll
        for (int k = 0; k < 8; k++) ov[k] = f2bf(val[k]);
        uint4 packed;
        packed.x = (unsigned)ov[0] | ((unsigned)ov[1] << 16);
        packed.y = (unsigned)ov[2] | ((unsigned)ov[3] << 16);
        packed.z = (unsigned)ov[4] | ((unsigned)ov[5] << 16);
        packed.w = (unsigned)ov[6] | ((unsigned)ov[7] << 16);
        ((uint4*)(hout + (size_t)v * O))[c] = packed;
    }
}

// ---------------- fused mean-pool + linear + sigmoid: one block per graph ----------------
__global__ __launch_bounds__(256) void pool_final_kernel(
    const unsigned short* __restrict__ h, const int* __restrict__ start,
    const float* __restrict__ lw, const float* __restrict__ lb,
    float* __restrict__ out, int G) {
    __shared__ float red[8][33];
    int g = blockIdx.x;
    if (g >= G) return;
    int beg = start[g], end = start[g + 1];
    int tid = threadIdx.x;
    int nodeLane = tid >> 5, f = tid & 31;
    float acc = 0.f;
    for (int v = beg + nodeLane; v < end; v += 8)
        acc += bf2f(h[(size_t)v * 32 + f]);
    red[nodeLane][f] = acc;
    __syncthreads();
    if (tid < 32) {
        float s = 0.f;
#pragma unroll
        for (int i = 0; i < 8; i++) s += red[i][f];
        float inv = 1.f / fmaxf((float)(end - beg), 1.f);
        float val = s * inv * lw[f];
#pragma unroll
        for (int o = 16; o > 0; o >>= 1) val += __shfl_xor(val, o);
        if (f == 0) out[g] = 1.f / (1.f + __expf(-(val + lb[0])));
    }
}

extern "C" void kernel_launch(void* const* d_in, const int* in_sizes, int n_in,
                              void* d_out, int out_size, void* d_ws, size_t ws_size,
                              hipStream_t stream) {
    const float* x = (const float*)d_in[0];
    const int* ei = (const int*)d_in[1];
    const int* batch = (const int*)d_in[2];
    const float* w1 = (const float*)d_in[3];
    const float* b1 = (const float*)d_in[4];
    const float* w2 = (const float*)d_in[5];
    const float* b2 = (const float*)d_in[6];
    const float* w3 = (const float*)d_in[7];
    const float* b3 = (const float*)d_in[8];
    const float* gw[5];
    const float* gas[5];
    const float* gad[5];
    const float* gb[5];
    for (int l = 0; l < 5; l++) {
        gw[l] = (const float*)d_in[9 + l * 4 + 0];
        gas[l] = (const float*)d_in[9 + l * 4 + 1];
        gad[l] = (const float*)d_in[9 + l * 4 + 2];
        gb[l] = (const float*)d_in[9 + l * 4 + 3];
    }
    const float* lw = (const float*)d_in[29];
    const float* lb = (const float*)d_in[30];
    float* out = (float*)d_out;

    int N = in_sizes[0];
    int E = in_sizes[1] / 2;
    int G = out_size;
    int Etot = E + N;

    char* ws = (char*)d_ws;
    size_t off = 0;
    auto alloc = [&](size_t bytes) -> void* {
        void* p = ws + off;
        off = (off + bytes + 255) & ~(size_t)255;
        return p;
    };
    unsigned short* actA = (unsigned short*)alloc((size_t)N * 256 * 2);
    unsigned short* actB = (unsigned short*)alloc((size_t)N * 256 * 2);
    float* logit0 = (float*)alloc((size_t)N * 8);  // as|ad ping
    float* logit1 = (float*)alloc((size_t)N * 8);  // as|ad pong
    int* deg = (int*)alloc((size_t)N * 4);
    int* rowptr = (int*)alloc((size_t)(N + 1) * 4);
    int* cursor = (int*)alloc((size_t)(N + 1) * 4);
    int* esrc = (int*)alloc((size_t)Etot * 4);
    int* bsums = (int*)alloc(4096);
    int* gstart = (int*)alloc((size_t)(G + 1) * 4);
    unsigned short* wbAll = (unsigned short*)alloc((size_t)83968 * 2);
    float* uAll = (float*)alloc((size_t)1280 * 4);
    const int woff[5] = {0, 8192, 40960, 73728, 81920};
    const int uoff[5] = {0, 64, 192, 448, 576};
    unsigned short* wb[5];
    for (int l = 0; l < 5; l++) wb[l] = wbAll + woff[l];
    (void)ws_size;
    (void)n_in;

    // 0. zero deg only
    hipMemsetAsync(deg, 0, (size_t)N * 4, stream);

    // 1. prelude
    int mlpB = (N + 255) / 256;
    int gsB = (G + 1 + 255) / 256;
    int histB = (Etot + 255) / 256;
    prelude_kernel<<<mlpB + F2BF_B + gsB + U_B + histB, 256, 0, stream>>>(
        x, w1, b1, w2, b2, w3, b3, actA, N, gw[0], gw[1], gw[2], gw[3], gw[4], wbAll,
        gas[0], gas[1], gas[2], gas[3], gas[4], gad[0], gad[1], gad[2], gad[3], gad[4], uAll,
        batch, gstart, G, ei + E, deg, E, mlpB, gsB);

    // 2. CSR scan + scatter
    int nb = (N + 1023) / 1024;
    scan_block_sums<<<nb, 256, 0, stream>>>(deg, bsums, N);
    scan_write<<<nb, 256, 0, stream>>>(deg, bsums, rowptr, cursor, N, nb);
    scatter_kernel<<<(Etot + 255) / 256, 256, 0, stream>>>(ei, ei + E, cursor, esrc, E, N);

    // 3. five GAT layers; layer-l logits live in buf[l&1]; gemm0 produces layer-0 logits,
    //    each aggregate produces the next layer's logits from its in-register output.
    const int Ks[5] = {64, 128, 256, 128, 64};
    const int Os[5] = {128, 256, 128, 64, 32};
    int aggBlocks = (N + 3) / 4;
    int gx = (N + 127) / 128;
    for (int l = 0; l < 5; l++) {
        int K = Ks[l], O = Os[l];
        float* lg = (l & 1) ? logit1 : logit0;      // this layer's logits
        float* lgn = (l & 1) ? logit0 : logit1;     // next layer's logits
        const float* gus = (l == 0) ? uAll + uoff[0] : nullptr;
        const float* gud = (l == 0) ? uAll + 640 + uoff[0] : nullptr;
        const float* usn = (l < 4) ? uAll + uoff[l + 1] : nullptr;
        const float* udn = (l < 4) ? uAll + 640 + uoff[l + 1] : nullptr;
        if (O >= 64) {
            dim3 grid(gx, O / 64);
            gemm_mfma<64><<<grid, 256, 0, stream>>>(actA, wb[l], actB, gus, gud, lg, lg + N, N,
                                                    K, O);
        } else {
            dim3 grid(gx, 1);
            gemm_mfma<32><<<grid, 256, 0, stream>>>(actA, wb[l], actB, gus, gud, lg, lg + N, N,
                                                    K, O);
        }
        switch (O) {
            case 256:
                gat_aggregate<256><<<aggBlocks, 256, 0, stream>>>(
                    actB, lg, lg + N, rowptr, esrc, gb[l], actA, N, usn, udn, lgn, lgn + N);
                break;
            case 128:
                gat_aggregate<128><<<aggBlocks, 256, 0, stream>>>(
                    actB, lg, lg + N, rowptr, esrc, gb[l], actA, N, usn, udn, lgn, lgn + N);
                break;
            case 64:
                gat_aggregate<64><<<aggBlocks, 256, 0, stream>>>(
                    actB, lg, lg + N, rowptr, esrc, gb[l], actA, N, usn, udn, lgn, lgn + N);
                break;
            default:
                gat_aggregate<32><<<aggBlocks, 256, 0, stream>>>(
                    actB, lg, lg + N, rowptr, esrc, gb[l], actA, N, usn, udn, lgn, lgn + N);
                break;
        }
    }

    // 4. fused mean pool + linear + sigmoid
    pool_final_kernel<<<G, 256, 0, stream>>>(actA, gstart, lw, lb, out, G);
}